// Round 6
// baseline (102.158 us; speedup 1.0000x reference)
//
#include <hip/hip_runtime.h>
#include <stdint.h>

// VQ codebook assignment via split-precision bf16 MFMA:
//   argmin_k ||z-c_k||^2 == argmin_k (csq[k] - 2 z.c_k)
//   z.c ~= z_hi.c_hi + z_lo.c_hi + z_hi.c_lo   (bf16 hi/lo split, K_eff=768)
// Round-6: loop interchange. Outer kk, 2 code-tiles resident in acc regs:
// z frags read once per kk per pass (halves LDS reads), 48-MFMA straight-line
// runs with 8 independent L2 B-loads hoistable above them. 1 block/CU
// (8 waves, VGPR-resident acc). No barriers in main loop. fp64 fixup.

#define NQ 32768
#define ND 256
#define NK 1024
#define TAU 0.0078125f   // 2^-7 margin threshold for the exact-fixup path

typedef short bf16x8 __attribute__((ext_vector_type(8)));
typedef float f32x4  __attribute__((ext_vector_type(4)));

// ws layout (bytes); total ~1.19 MB
// cbw: ushort [64 koct][1024 codes][8]; koct 0..31 = c_hi octet, 32..63 = c_lo
#define WS_CBW 0
#define WS_CSQ (64 * 1024 * 8 * 2)       // 1 MB; then double csq[1024]
#define WS_CNT (WS_CSQ + 1024 * 8)
#define WS_LST (WS_CNT + 16)
#define WS_NEEDED (WS_LST + NQ * 4)

__device__ __forceinline__ ushort bf_trunc(float x) {
    return (ushort)(__builtin_bit_cast(uint32_t, x) >> 16);
}
__device__ __forceinline__ float bf_back(ushort h) {
    return __builtin_bit_cast(float, ((uint32_t)h) << 16);
}

// ---------------------------------------------------------------- prep ----
// 256 blocks x 256 threads; each wave converts one code row (4 codes/block).
__global__ __launch_bounds__(256)
void vq_prep(const float* __restrict__ cb, uint8_t* __restrict__ ws)
{
    ushort* cbw = (ushort*)(ws + WS_CBW);
    double* csq = (double*)(ws + WS_CSQ);
    int*    cnt = (int*)(ws + WS_CNT);

    const int tid  = threadIdx.x;
    const int code = blockIdx.x * 4 + (tid >> 6);
    const int lane = tid & 63;
    if (blockIdx.x == 0 && tid == 0) *cnt = 0;   // re-zero (determinism)

    const int d0 = lane * 4;
    const float4 v = *reinterpret_cast<const float4*>(&cb[(size_t)code * ND + d0]);
    const float xs[4] = {v.x, v.y, v.z, v.w};

    ushort4 h4, l4;
    ushort* hp = &h4.x; ushort* lp = &l4.x;
    double ss = 0.0;
    #pragma unroll
    for (int j = 0; j < 4; ++j) {
        const ushort h = bf_trunc(xs[j]);
        hp[j] = h;
        lp[j] = bf_trunc(xs[j] - bf_back(h));
        ss += (double)xs[j] * (double)xs[j];
    }

    const int oct = d0 >> 3;             // 0..31
    const int off = d0 & 7;              // 0 or 4
    *reinterpret_cast<ushort4*>(&cbw[((size_t)oct * NK + code) * 8 + off]) = h4;
    *reinterpret_cast<ushort4*>(&cbw[((size_t)(32 + oct) * NK + code) * 8 + off]) = l4;

    #pragma unroll
    for (int m = 1; m < 64; m <<= 1) ss += __shfl_xor(ss, m);
    if (lane == 0) csq[code] = ss;
}

// ---------------------------------------------------------------- main ----
// 512 threads = 8 waves; block = 64 queries x 1024 codes.
// Wave owns a 32-code stripe per code-tile; 2 passes x 2 resident tiles.
__global__ __launch_bounds__(512, 2)
void vq_main(const float* __restrict__ z, const float* __restrict__ cb,
             uint8_t* __restrict__ ws, float* __restrict__ out)
{
    __shared__ ushort zt[64][512];        // z hi(units 0..31)|lo(32..63), XOR-swizzled
    __shared__ float  csq_l[NK];
    __shared__ float  wb1[8][64], wb2[8][64];
    __shared__ int    wbi[8][64];
    __shared__ int    qidx[64];

    const ushort* cbw  = (const ushort*)(ws + WS_CBW);
    const double* csqd = (const double*)(ws + WS_CSQ);
    int* cnt = (int*)(ws + WS_CNT);
    int* lst = (int*)(ws + WS_LST);

    const int tid  = threadIdx.x;
    const int lane = tid & 63;
    const int w    = tid >> 6;            // wave 0..7 -> 32-code stripe per tile
    const int cl   = lane & 15;
    const int g    = lane >> 4;           // quarter 0..3 (k-octet / code-row group)
    const int q0   = blockIdx.x * 64;

    // --- stage z tile: 64q x 256d fp32 -> hi/lo bf16, swizzled 16B units
    {
        const int rr = tid >> 6;
        const int c4 = (tid & 63) * 4;
        const int uh = c4 >> 3;           // hi unit 0..31
        const int ul = (256 + c4) >> 3;   // lo unit 32..63
        #pragma unroll
        for (int it = 0; it < 8; ++it) {
            const int q = it * 8 + rr;
            const float4 v = *reinterpret_cast<const float4*>(
                &z[(size_t)(q0 + q) * ND + c4]);
            const float xs[4] = {v.x, v.y, v.z, v.w};
            ushort4 h4, l4;
            ushort* hp = &h4.x; ushort* lp = &l4.x;
            #pragma unroll
            for (int j = 0; j < 4; ++j) {
                const ushort h = bf_trunc(xs[j]);
                hp[j] = h;
                lp[j] = bf_trunc(xs[j] - bf_back(h));
            }
            const int sw = q & 7;
            *reinterpret_cast<ushort4*>(&zt[q][((uh ^ sw) << 3) + (c4 & 7)]) = h4;
            *reinterpret_cast<ushort4*>(&zt[q][((ul ^ sw) << 3) + (c4 & 7)]) = l4;
        }
    }
    #pragma unroll
    for (int i = 0; i < 2; ++i)
        csq_l[i * 512 + tid] = (float)csqd[i * 512 + tid];
    __syncthreads();

    // per-lane running top-2, one slot per q-tile (q = qt*16 + cl)
    float b1[4], b2[4]; int bidx[4];
    #pragma unroll
    for (int s = 0; s < 4; ++s) { b1[s] = 3.0e38f; b2[s] = 3.0e38f; bidx[s] = 0; }

    #pragma unroll 1
    for (int pass = 0; pass < 2; ++pass) {
        f32x4 acc[2][2][4];               // [ctl][cm][qt]
        #pragma unroll
        for (int ctl = 0; ctl < 2; ++ctl)
            #pragma unroll
            for (int cm = 0; cm < 2; ++cm)
                #pragma unroll
                for (int qt = 0; qt < 4; ++qt)
                    acc[ctl][cm][qt] = (f32x4){0.f, 0.f, 0.f, 0.f};

        #pragma unroll 1
        for (int kk = 0; kk < 8; ++kk) {
            // codebook frags (A-operand), direct from L2: 2 tiles x 2 rows, hi+lo
            bf16x8 cfh[2][2], cfl[2][2];
            #pragma unroll
            for (int ctl = 0; ctl < 2; ++ctl) {
                const int cbase = (pass * 2 + ctl) * 256 + w * 32;
                #pragma unroll
                for (int cm = 0; cm < 2; ++cm) {
                    const int code = cbase + cm * 16 + cl;
                    const int oh   = kk * 4 + g;
                    cfh[ctl][cm] = *reinterpret_cast<const bf16x8*>(
                        &cbw[((size_t)oh * NK + code) * 8]);
                    cfl[ctl][cm] = *reinterpret_cast<const bf16x8*>(
                        &cbw[((size_t)(32 + oh) * NK + code) * 8]);
                }
            }
            // z frags (B-operand) from LDS: hi & lo, 4 q-tiles (read ONCE per kk)
            bf16x8 zfh[4], zfl[4];
            #pragma unroll
            for (int qt = 0; qt < 4; ++qt) {
                const int q  = qt * 16 + cl;
                const int uh = (kk * 4 + g) ^ (q & 7);
                const int ul = (32 + kk * 4 + g) ^ (q & 7);
                zfh[qt] = *reinterpret_cast<const bf16x8*>(&zt[q][uh << 3]);
                zfl[qt] = *reinterpret_cast<const bf16x8*>(&zt[q][ul << 3]);
            }
            // 48 MFMA straight-line: hi*hi + hi*lo(z) + lo(c)*hi
            #pragma unroll
            for (int ctl = 0; ctl < 2; ++ctl)
                #pragma unroll
                for (int cm = 0; cm < 2; ++cm)
                    #pragma unroll
                    for (int qt = 0; qt < 4; ++qt) {
                        acc[ctl][cm][qt] = __builtin_amdgcn_mfma_f32_16x16x32_bf16(
                            cfh[ctl][cm], zfh[qt], acc[ctl][cm][qt], 0, 0, 0);
                        acc[ctl][cm][qt] = __builtin_amdgcn_mfma_f32_16x16x32_bf16(
                            cfh[ctl][cm], zfl[qt], acc[ctl][cm][qt], 0, 0, 0);
                        acc[ctl][cm][qt] = __builtin_amdgcn_mfma_f32_16x16x32_bf16(
                            cfl[ctl][cm], zfh[qt], acc[ctl][cm][qt], 0, 0, 0);
                    }
        }

        // fold both resident tiles into the running top-2
        #pragma unroll
        for (int ctl = 0; ctl < 2; ++ctl) {
            const int cbase = (pass * 2 + ctl) * 256 + w * 32;
            #pragma unroll
            for (int cm = 0; cm < 2; ++cm) {
                const int kb = cbase + cm * 16 + g * 4;
                const float4 cs4 = *reinterpret_cast<const float4*>(&csq_l[kb]);
                const float css[4] = {cs4.x, cs4.y, cs4.z, cs4.w};
                #pragma unroll
                for (int qt = 0; qt < 4; ++qt)
                    #pragma unroll
                    for (int r = 0; r < 4; ++r) {
                        const float d = fmaf(-2.0f, acc[ctl][cm][qt][r], css[r]);
                        if (d < b1[qt]) { b2[qt] = b1[qt]; b1[qt] = d; bidx[qt] = kb + r; }
                        else if (d < b2[qt]) b2[qt] = d;
                    }
            }
        }
    }

    // --- combine the 4 quarters (same q = qt*16+cl, different codes)
    #pragma unroll
    for (int qt = 0; qt < 4; ++qt) {
        float B1 = b1[qt], B2 = b2[qt]; int BI = bidx[qt];
        #pragma unroll
        for (int m = 16; m < 64; m <<= 1) {
            const float o1 = __shfl_xor(B1, m);
            const float o2 = __shfl_xor(B2, m);
            const int   oi = __shfl_xor(BI, m);
            const float n2 = fminf(fmaxf(B1, o1), fminf(B2, o2));
            const bool sel = (o1 < B1) || (o1 == B1 && oi < BI);
            B1 = fminf(B1, o1); BI = sel ? oi : BI; B2 = n2;
        }
        if (g == 0) {
            const int q = qt * 16 + cl;
            wb1[w][q] = B1; wb2[w][q] = B2; wbi[w][q] = BI;
        }
    }
    __syncthreads();

    // --- combine 8 wave candidates, flag tight margins
    if (tid < 64) {
        float B1 = wb1[0][tid], B2 = wb2[0][tid]; int BI = wbi[0][tid];
        #pragma unroll
        for (int ww = 1; ww < 8; ++ww) {
            const float o1 = wb1[ww][tid], o2 = wb2[ww][tid];
            const int   oi = wbi[ww][tid];
            const float n2 = fminf(fmaxf(B1, o1), fminf(B2, o2));
            const bool sel = (o1 < B1) || (o1 == B1 && oi < BI);
            B1 = fminf(B1, o1); BI = sel ? oi : BI; B2 = n2;
        }
        qidx[tid] = BI;
        if (B2 - B1 < TAU) {
            const int pos = atomicAdd(cnt, 1);
            lst[pos] = q0 + tid;
        }
    }
    __syncthreads();

    // --- gather: out[q][:] = cb[idx[q]][:]
    {
        const int rr = tid >> 6;
        const int c  = (tid & 63) * 4;
        #pragma unroll
        for (int it = 0; it < 8; ++it) {
            const int q = it * 8 + rr;
            const int k = qidx[q];
            *reinterpret_cast<float4*>(&out[(size_t)(q0 + q) * ND + c]) =
                *reinterpret_cast<const float4*>(&cb[(size_t)k * ND + c]);
        }
    }
}

// --------------------------------------------------------------- fixup ----
// Exact fp64 re-solve for flagged (tight-margin) queries.
__global__ __launch_bounds__(256, 1)
void vq_fix(const float* __restrict__ z, const float* __restrict__ cb,
            uint8_t* __restrict__ ws, float* __restrict__ out)
{
    __shared__ double zd[ND];
    __shared__ double rb[256];
    __shared__ int    ri[256];

    const int* cnt = (const int*)(ws + WS_CNT);
    const int* lst = (const int*)(ws + WS_LST);
    const int tid = threadIdx.x;
    const int n = *cnt;

    for (int i = blockIdx.x; i < n; i += gridDim.x) {
        const int q = lst[i];
        __syncthreads();
        zd[tid] = (double)z[(size_t)q * ND + tid];
        __syncthreads();

        double best = 1.0e300; int bi = 0;
        #pragma unroll 1
        for (int j = 0; j < 4; ++j) {
            const int k = tid * 4 + j;
            double s = 0.0;
            const float* row = &cb[(size_t)k * ND];
            for (int d = 0; d < ND; ++d) {
                const double df = zd[d] - (double)row[d];
                s = fma(df, df, s);
            }
            if (s < best) { best = s; bi = k; }
        }
        rb[tid] = best; ri[tid] = bi;
        __syncthreads();
        for (int m = 128; m > 0; m >>= 1) {
            if (tid < m) {
                if (rb[tid + m] < rb[tid] ||
                    (rb[tid + m] == rb[tid] && ri[tid + m] < ri[tid])) {
                    rb[tid] = rb[tid + m]; ri[tid] = ri[tid + m];
                }
            }
            __syncthreads();
        }
        const int k = ri[0];
        if (tid < 64) {
            const float4 vv = *reinterpret_cast<const float4*>(
                &cb[(size_t)k * ND + tid * 4]);
            *reinterpret_cast<float4*>(&out[(size_t)q * ND + tid * 4]) = vv;
        }
        __syncthreads();
    }
}

// ------------------------------------------------- fallback (round-1) -----
// Verified-passing fp32 VALU kernel, used only if ws_size is insufficient.
__global__ __launch_bounds__(256, 2)
void vq_fallback(const float* __restrict__ z, const float* __restrict__ cb,
                 float* __restrict__ out)
{
    __shared__ float z_t[ND][64];
    __shared__ float cb_t[32][64];
    __shared__ float csq[NK];
    __shared__ int   idx_lds[64];

    const int tid = threadIdx.x;
    const int tx  = tid & 15;
    const int ty  = tid >> 4;
    const int q0  = blockIdx.x * 64;

    {
        const int r  = tid >> 6;
        const int c4 = (tid & 63) * 4;
        #pragma unroll
        for (int it = 0; it < 16; ++it) {
            const int q = it * 4 + r;
            const float4 v = *reinterpret_cast<const float4*>(
                &z[(size_t)(q0 + q) * ND + c4]);
            const float vv[4] = {v.x, v.y, v.z, v.w};
            #pragma unroll
            for (int j = 0; j < 4; ++j) {
                const int d = c4 + j;
                const int s = 4 * ((d >> 2) & 7);
                z_t[d][q ^ s] = vv[j];
            }
        }
    }
    {
        const int lane16 = tid & 15;
        const int rgrp   = tid >> 4;
        #pragma unroll 4
        for (int it = 0; it < 64; ++it) {
            const int k = it * 16 + rgrp;
            double ssum = 0.0;
            #pragma unroll
            for (int h = 0; h < 4; ++h) {
                const float4 v = *reinterpret_cast<const float4*>(
                    &cb[(size_t)k * ND + lane16 * 16 + h * 4]);
                ssum += (double)v.x * v.x + (double)v.y * v.y
                      + (double)v.z * v.z + (double)v.w * v.w;
            }
            #pragma unroll
            for (int m = 8; m >= 1; m >>= 1) ssum += __shfl_xor(ssum, m);
            if (lane16 == 0) csq[k] = (float)ssum;
        }
    }

    double bestd[4]; int besti[4];
    #pragma unroll
    for (int i = 0; i < 4; ++i) { bestd[i] = 1e300; besti[i] = 0; }

    for (int kt = 0; kt < 16; ++kt) {
        double acc[4][4];
        #pragma unroll
        for (int i = 0; i < 4; ++i)
            #pragma unroll
            for (int j = 0; j < 4; ++j) acc[i][j] = 0.0;

        for (int dc = 0; dc < 8; ++dc) {
            __syncthreads();
            {
                const int kk = tid >> 3;
                const int dd = (tid & 7) * 4;
                #pragma unroll
                for (int h = 0; h < 2; ++h) {
                    const int k = kk + h * 32;
                    const float4 v = *reinterpret_cast<const float4*>(
                        &cb[(size_t)(kt * 64 + k) * ND + dc * 32 + dd]);
                    const float vv[4] = {v.x, v.y, v.z, v.w};
                    #pragma unroll
                    for (int j = 0; j < 4; ++j) {
                        const int d = dd + j;
                        const int s = 4 * ((d >> 2) & 7);
                        cb_t[d][k ^ s] = vv[j];
                    }
                }
            }
            __syncthreads();

            float cr[4][4];
            #pragma unroll
            for (int i = 0; i < 4; ++i)
                #pragma unroll
                for (int j = 0; j < 4; ++j) cr[i][j] = 0.0f;

            #pragma unroll 8
            for (int d = 0; d < 32; ++d) {
                const int s  = 4 * ((d >> 2) & 7);
                const int dg = dc * 32 + d;
                const float4 zv4 = *reinterpret_cast<const float4*>(
                    &z_t[dg][(4 * ty) ^ s]);
                const float4 cv4 = *reinterpret_cast<const float4*>(
                    &cb_t[d][(4 * tx) ^ s]);
                const float zv[4] = {zv4.x, zv4.y, zv4.z, zv4.w};
                const float cv[4] = {cv4.x, cv4.y, cv4.z, cv4.w};
                #pragma unroll
                for (int i = 0; i < 4; ++i)
                    #pragma unroll
                    for (int j = 0; j < 4; ++j)
                        cr[i][j] = fmaf(zv[i], cv[j], cr[i][j]);
            }
            #pragma unroll
            for (int i = 0; i < 4; ++i)
                #pragma unroll
                for (int j = 0; j < 4; ++j)
                    acc[i][j] += (double)cr[i][j];
        }

        #pragma unroll
        for (int j = 0; j < 4; ++j) {
            const int k = kt * 64 + tx * 4 + j;
            const double cs = (double)csq[k];
            #pragma unroll
            for (int i = 0; i < 4; ++i) {
                const double dist = cs - 2.0 * acc[i][j];
                if (dist < bestd[i]) { bestd[i] = dist; besti[i] = k; }
            }
        }
    }

    #pragma unroll
    for (int i = 0; i < 4; ++i) {
        double bd = bestd[i]; int bi = besti[i];
        #pragma unroll
        for (int m = 8; m >= 1; m >>= 1) {
            const double od = __shfl_xor(bd, m);
            const int    oi = __shfl_xor(bi, m);
            if (od < bd || (od == bd && oi < bi)) { bd = od; bi = oi; }
        }
        if (tx == 0) idx_lds[ty * 4 + i] = bi;
    }
    __syncthreads();

    {
        const int r = tid >> 6;
        const int c = (tid & 63) * 4;
        #pragma unroll
        for (int it = 0; it < 16; ++it) {
            const int q = it * 4 + r;
            const int k = idx_lds[q];
            const float4 v = *reinterpret_cast<const float4*>(
                &cb[(size_t)k * ND + c]);
            *reinterpret_cast<float4*>(&out[(size_t)(q0 + q) * ND + c]) = v;
        }
    }
}

extern "C" void kernel_launch(void* const* d_in, const int* in_sizes, int n_in,
                              void* d_out, int out_size, void* d_ws, size_t ws_size,
                              hipStream_t stream)
{
    const float* z   = (const float*)d_in[0];   // [B,T,D] fp32
    const float* cbk = (const float*)d_in[1];   // [K,D]  fp32
    float* out = (float*)d_out;
    uint8_t* ws = (uint8_t*)d_ws;

    if (ws_size < (size_t)WS_NEEDED) {
        vq_fallback<<<NQ / 64, 256, 0, stream>>>(z, cbk, out);
        return;
    }

    vq_prep<<<NK / 4, 256, 0, stream>>>(cbk, ws);
    vq_main<<<NQ / 64, 512, 0, stream>>>(z, cbk, ws, out);
    vq_fix<<<64, 256, 0, stream>>>(z, cbk, ws, out);
}